// Round 19
// baseline (142.916 us; speedup 1.0000x reference)
//
#include <hip/hip_runtime.h>
#include <math.h>

typedef _Float16 f16x8 __attribute__((ext_vector_type(8)));
typedef _Float16 f16x4 __attribute__((ext_vector_type(4)));
typedef float    f32x4 __attribute__((ext_vector_type(4)));

constexpr int kB  = 4;
constexpr int kN  = 512;
constexpr int kE  = 512;
constexpr int kH  = 8;
constexpr int kH2 = 16;
constexpr int kC  = 64;
constexpr int kDV = 64;
constexpr float kLamInit = 0.2f;

// ---- prep2 (R8/R14-validated): f32->f16 cvt, lambda, umask bitpack ---------
__global__ __launch_bounds__(256) void prep2_kernel(
    const float* __restrict__ x, const float* __restrict__ vw,
    const float* __restrict__ ow, const int* __restrict__ umask,
    const float* __restrict__ lq1, const float* __restrict__ lk1,
    const float* __restrict__ lq2, const float* __restrict__ lk2,
    _Float16* __restrict__ x16, _Float16* __restrict__ w16v,
    _Float16* __restrict__ w16o, unsigned short* __restrict__ mbits,
    float* __restrict__ lam_out) {
  const int bid = blockIdx.x;
  if (bid < 1536) {
    const float* src; _Float16* dst; int base;
    if (bid < 1024)      { src = x;  dst = x16;  base = bid; }
    else if (bid < 1280) { src = vw; dst = w16v; base = bid - 1024; }
    else                 { src = ow; dst = w16o; base = bid - 1280; }
    const int i = base * 256 + threadIdx.x;
    const float4 v = ((const float4*)src)[i];
    union { _Float16 h[4]; uint2 u2; } P;
    P.h[0]=(_Float16)v.x; P.h[1]=(_Float16)v.y;
    P.h[2]=(_Float16)v.z; P.h[3]=(_Float16)v.w;
    *(uint2*)(dst + i * 4) = P.u2;
  } else if (bid == 1536) {
    if (threadIdx.x < 64) {
      float s1 = 0.f, s2 = 0.f;
      for (int i = threadIdx.x; i < kE; i += 64) { s1 += lq1[i]*lk1[i]; s2 += lq2[i]*lk2[i]; }
      #pragma unroll
      for (int o = 32; o; o >>= 1) { s1 += __shfl_xor(s1, o); s2 += __shfl_xor(s2, o); }
      if (threadIdx.x == 0) lam_out[0] = expf(s1) - expf(s2) + kLamInit;
    }
  } else {
    const int i = (bid - 1537) * 256 + threadIdx.x;  // (b*kN+k)*kN+q
    const int4* src = (const int4*)(umask + (size_t)i * kH2);
    unsigned int w = 0;
    #pragma unroll
    for (int c = 0; c < 4; ++c) {
      const int4 m = src[c];
      w |= (m.x & 1) << (c * 4 + 0);
      w |= (m.y & 1) << (c * 4 + 1);
      w |= (m.z & 1) << (c * 4 + 2);
      w |= (m.w & 1) << (c * 4 + 3);
    }
    mbits[i] = (unsigned short)w;
  }
}

// ---- hgemmT_v (R7-validated): Vt[b][h][d][n] = (x @ v_w^T)^T ---------------
__global__ __launch_bounds__(256) void hgemmT_v(const _Float16* __restrict__ W16,
                                                const _Float16* __restrict__ X16,
                                                _Float16* __restrict__ Vt) {
  const int tid = threadIdx.x, lane = tid & 63, wv = tid >> 6;
  const int l15 = lane & 15, l4 = lane >> 4;
  const int f0 = blockIdx.y * 64 + wv * 16;
  const int n0 = blockIdx.x * 64;
  f32x4 acc[4] = {{0,0,0,0},{0,0,0,0},{0,0,0,0},{0,0,0,0}};
  const _Float16* Ap = W16 + (size_t)(f0 + l15) * kE + l4 * 8;
  const _Float16* Bp = X16 + (size_t)(n0 + l15) * kE + l4 * 8;
  for (int k0 = 0; k0 < kE; k0 += 32) {
    const f16x8 af = *(const f16x8*)(Ap + k0);
    #pragma unroll
    for (int t = 0; t < 4; ++t) {
      const f16x8 bf = *(const f16x8*)(Bp + (size_t)t * 16 * kE + k0);
      acc[t] = __builtin_amdgcn_mfma_f32_16x16x32_f16(af, bf, acc[t], 0, 0, 0);
    }
  }
  #pragma unroll
  for (int t = 0; t < 4; ++t)
    #pragma unroll
    for (int r = 0; r < 4; ++r) {
      const int f  = f0 + l4 * 4 + r;
      const int ng = n0 + t * 16 + l15;
      const int bb = ng >> 9, n = ng & 511;
      Vt[(((size_t)((bb * kH + (f >> 6)) * kDV) + (f & 63)) * kN) + n] = (_Float16)acc[t][r];
    }
}

// ---- fused v11: 256-thr blocks (4 waves, wave = 2 heads), kh=8 -------------
// grid (qt 32, kh 8, b 4) = 1024 blocks -> 4 blocks/CU = 16 waves/CU in FOUR
// independent barrier domains (vs R14's two). Per 32-k tile:
// phase A: wave produces k = k0 + wv*8 + [0,8) (2 halves of 4) -> P. barrier.
// phase B: wave's heads h = 2wv, 2wv+1: A = Vt rows, B = P. barrier.
// All layouts byte-identical to validated R6/R14 pieces.
__global__ __launch_bounds__(256, 4) void fused_attn11(
    const float* __restrict__ u, const unsigned short* __restrict__ mbits,
    const float* __restrict__ uw, const float* __restrict__ ub,
    const _Float16* __restrict__ Vt,
    _Float16* __restrict__ Opart, float* __restrict__ Spart) {
  __shared__ _Float16 P[16 * 648];
  __shared__ float S_lds[4][16][17];
  const int tid = threadIdx.x, lane = tid & 63, wv = tid >> 6;  // wv 0..3
  const int l15 = lane & 15, l4 = lane >> 4;
  const int qt = blockIdx.x, kh = blockIdx.y, b = blockIdx.z;
  const int q0 = qt * 16;
  const int kstart = kh * 64;

  f16x8 bfrag[2];
  #pragma unroll
  for (int ch = 0; ch < 2; ++ch) {
    const float* wp = uw + l15 * 64 + ch * 32 + l4 * 8;
    const float4 wa = *(const float4*)wp;
    const float4 wb = *(const float4*)(wp + 4);
    f16x8 bf;
    bf[0]=(_Float16)wa.x; bf[1]=(_Float16)wa.y; bf[2]=(_Float16)wa.z; bf[3]=(_Float16)wa.w;
    bf[4]=(_Float16)wb.x; bf[5]=(_Float16)wb.y; bf[6]=(_Float16)wb.z; bf[7]=(_Float16)wb.w;
    bfrag[ch] = bf;
  }
  const float bias = ub[l15];

  const unsigned short* mb0 = mbits + (size_t)(b * kN) * kN + q0 + l4 * 4;

  float s_acc[4] = {};
  f32x4 oacc[2][2][4];  // [hp][s][dt]
  #pragma unroll
  for (int a = 0; a < 2; ++a)
    #pragma unroll
    for (int s = 0; s < 2; ++s)
      #pragma unroll
      for (int d = 0; d < 4; ++d) oacc[a][s][d] = (f32x4){0.f, 0.f, 0.f, 0.f};

  for (int t = 0; t < 2; ++t) {
    const int k0 = kstart + t * 32;
    const int kbase = k0 + wv * 8;
    // ---- phase A: this wave's 8 k's, as 2 halves of 4 ----
    #pragma unroll
    for (int half = 0; half < 2; ++half) {
      _Float16 vals[4][4];
      #pragma unroll
      for (int kk = 0; kk < 4; ++kk) {
        const int k = kbase + half * 4 + kk;
        const unsigned long long pm =
            *(const unsigned long long*)(mb0 + (size_t)k * kN);
        const float* up = u + (((size_t)(b * kN + k)) * kN + q0 + l15) * kC + l4 * 8;
        f32x4 acc = {0.f, 0.f, 0.f, 0.f};
        #pragma unroll
        for (int ch = 0; ch < 2; ++ch) {
          const float4 a0 = *(const float4*)(up + ch * 32);
          const float4 a1 = *(const float4*)(up + ch * 32 + 4);
          f16x8 af;
          af[0]=(_Float16)a0.x; af[1]=(_Float16)a0.y; af[2]=(_Float16)a0.z; af[3]=(_Float16)a0.w;
          af[4]=(_Float16)a1.x; af[5]=(_Float16)a1.y; af[6]=(_Float16)a1.z; af[7]=(_Float16)a1.w;
          acc = __builtin_amdgcn_mfma_f32_16x16x32_f16(af, bfrag[ch], acc, 0, 0, 0);
        }
        #pragma unroll
        for (int r = 0; r < 4; ++r) {
          const float e = ((pm >> (r * 16 + l15)) & 1ULL) ? 0.f : __expf(acc[r] + bias);
          s_acc[r] += e;
          vals[r][kk] = (_Float16)e;
        }
      }
      #pragma unroll
      for (int r = 0; r < 4; ++r) {
        union { _Float16 h[4]; uint2 u2; } PK;
        #pragma unroll
        for (int kk = 0; kk < 4; ++kk) PK.h[kk] = vals[r][kk];
        *(uint2*)&P[l15 * 648 + (l4 * 4 + r) * 40 + wv * 8 + half * 4] = PK.u2;
      }
    }
    __syncthreads();  // all P writes visible
    // ---- phase B: PV via MFMA; wave's heads h = 2wv, 2wv+1 ----
    #pragma unroll
    for (int hp = 0; hp < 2; ++hp) {
      const int h = wv * 2 + hp;
      #pragma unroll
      for (int dt = 0; dt < 4; ++dt) {
        const f16x8 va = *(const f16x8*)(Vt +
            (((size_t)((b * kH + h) * kDV + dt * 16 + l15)) * kN) + k0 + l4 * 8);
        #pragma unroll
        for (int s = 0; s < 2; ++s) {
          const f16x8 pb = *(const f16x8*)&P[(h * 2 + s) * 648 + l15 * 40 + l4 * 8];
          oacc[hp][s][dt] = __builtin_amdgcn_mfma_f32_16x16x32_f16(va, pb, oacc[hp][s][dt], 0, 0, 0);
        }
      }
    }
    __syncthreads();  // all P reads done before next tile's writes
  }

  // ---- epilogue ----
  #pragma unroll
  for (int r = 0; r < 4; ++r) S_lds[wv][l15][l4 * 4 + r] = s_acc[r];
  __syncthreads();
  const int blk = (b * 8 + kh) * 32 + qt;
  {
    const int h2 = tid >> 4, q = tid & 15;
    const float S = S_lds[0][h2][q] + S_lds[1][h2][q] + S_lds[2][h2][q] + S_lds[3][h2][q];
    Spart[(size_t)blk * 256 + h2 * 16 + q] = S;
  }
  _Float16* ob = Opart + (size_t)blk * 16384;
  #pragma unroll
  for (int hp = 0; hp < 2; ++hp) {
    const int h = wv * 2 + hp;
    #pragma unroll
    for (int s = 0; s < 2; ++s)
      #pragma unroll
      for (int dt = 0; dt < 4; ++dt)
        #pragma unroll
        for (int r = 0; r < 4; ++r)
          ob[((size_t)(s * 8 + h) * 64 + dt * 16 + l4 * 4 + r) * 16 + l15] =
              (_Float16)oacc[hp][s][dt][r];
  }
}

// ---- combine_out: combine (8 partials) + LN + out-projection GEMM ----------
__global__ __launch_bounds__(256) void combine_out(
    const _Float16* __restrict__ Opart, const float* __restrict__ Spart,
    const float* __restrict__ lam_p, const float* __restrict__ ln_w,
    const float* __restrict__ ln_b, const _Float16* __restrict__ w16o,
    float* __restrict__ out) {
  __shared__ _Float16 a_lds[16][520];
  __shared__ float vsh[64][17];
  __shared__ float inv_sh[2][16];
  const int tid = threadIdx.x;
  const int fh = blockIdx.x, qt = blockIdx.y, b = blockIdx.z;
  const float lam = lam_p[0];

  for (int h = 0; h < 8; ++h) {
    if (tid < 32) {
      const int s = tid >> 4, q = tid & 15;
      float S = 0.f;
      #pragma unroll
      for (int kh = 0; kh < 8; ++kh)
        S += Spart[(size_t)((b * 8 + kh) * 32 + qt) * 256 + (h * 2 + s) * 16 + q];
      inv_sh[s][q] = (s ? lam : 1.0f) / S;
    }
    float a0[4] = {}, a1[4] = {};
    #pragma unroll
    for (int kh = 0; kh < 8; ++kh) {
      const size_t base = (size_t)((b * 8 + kh) * 32 + qt) * 16384;
      const f16x4 p0 = *(const f16x4*)(Opart + base + (size_t)(0 * 8 + h) * 1024 + tid * 4);
      const f16x4 p1 = *(const f16x4*)(Opart + base + (size_t)(1 * 8 + h) * 1024 + tid * 4);
      #pragma unroll
      for (int j = 0; j < 4; ++j) { a0[j] += (float)p0[j]; a1[j] += (float)p1[j]; }
    }
    __syncthreads();  // inv_sh ready; prev head's vsh reads complete
    {
      const int d = tid >> 2, q0i = (tid & 3) * 4;
      #pragma unroll
      for (int j = 0; j < 4; ++j)
        vsh[d][q0i + j] = a0[j] * inv_sh[0][q0i + j] - a1[j] * inv_sh[1][q0i + j];
    }
    __syncthreads();
    const int q = tid >> 4, i = tid & 15;
    float vv[4], s1 = 0.f, s2 = 0.f;
    #pragma unroll
    for (int jj = 0; jj < 4; ++jj) {
      vv[jj] = vsh[i * 4 + jj][q];
      s1 += vv[jj]; s2 += vv[jj] * vv[jj];
    }
    #pragma unroll
    for (int o = 1; o < 16; o <<= 1) { s1 += __shfl_xor(s1, o); s2 += __shfl_xor(s2, o); }
    const float mu = s1 * (1.0f / kDV);
    const float var = s2 * (1.0f / kDV) - mu * mu;
    const float rstd = rsqrtf(var + 1e-5f);
    #pragma unroll
    for (int jj = 0; jj < 4; ++jj)
      a_lds[q][h * kDV + i * 4 + jj] =
          (_Float16)((vv[jj] - mu) * rstd * ln_w[i * 4 + jj] + ln_b[i * 4 + jj]);
  }
  __syncthreads();  // a_lds complete

  const int lane = tid & 63, wv = tid >> 6;
  const int l15 = lane & 15, l4 = lane >> 4;
  const int f0 = fh * 256 + wv * 64;
  f32x4 acc[4] = {{0,0,0,0},{0,0,0,0},{0,0,0,0},{0,0,0,0}};
  const _Float16* Wp = w16o + (size_t)(f0 + l15) * kE + l4 * 8;
  for (int k0 = 0; k0 < kE; k0 += 32) {
    const f16x8 af = *(const f16x8*)&a_lds[l15][k0 + l4 * 8];
    #pragma unroll
    for (int ft = 0; ft < 4; ++ft) {
      const f16x8 bf = *(const f16x8*)(Wp + (size_t)ft * 16 * kE + k0);
      acc[ft] = __builtin_amdgcn_mfma_f32_16x16x32_f16(af, bf, acc[ft], 0, 0, 0);
    }
  }
  #pragma unroll
  for (int ft = 0; ft < 4; ++ft)
    #pragma unroll
    for (int r = 0; r < 4; ++r)
      out[(size_t)(b * kN + qt * 16 + l4 * 4 + r) * kE + f0 + ft * 16 + l15] = acc[ft][r];
}

// ----------------------------------------------------------------------------
extern "C" void kernel_launch(void* const* d_in, const int* in_sizes, int n_in,
                              void* d_out, int out_size, void* d_ws, size_t ws_size,
                              hipStream_t stream) {
  const float* x     = (const float*)d_in[0];
  const float* u     = (const float*)d_in[1];
  const int*   umask = (const int*)d_in[2];
  const float* v_w   = (const float*)d_in[3];
  const float* out_w = (const float*)d_in[4];
  const float* uw    = (const float*)d_in[5];
  const float* ubias = (const float*)d_in[6];
  const float* lq1   = (const float*)d_in[7];
  const float* lk1   = (const float*)d_in[8];
  const float* lq2   = (const float*)d_in[9];
  const float* lk2   = (const float*)d_in[10];
  const float* ln_w  = (const float*)d_in[11];
  const float* ln_b  = (const float*)d_in[12];
  float* out = (float*)d_out;

  char* ws = (char*)d_ws;
  const size_t sz_half = (size_t)kB * kN * kE * 2;             // 2 MB
  const size_t sz_w16  = (size_t)kE * kE * 2;                  // 512 KB
  const size_t sz_op   = (size_t)1024 * 16384 * 2;             // 33.55 MB (f16)
  const size_t sz_sp   = (size_t)1024 * 256 * 4;               // 1 MB
  const size_t sz_mb   = (size_t)kB * kN * kN * 2;             // 2 MB
  const size_t off_x16 = 256;
  const size_t off_wv  = off_x16 + sz_half;
  const size_t off_wo  = off_wv + sz_w16;
  const size_t off_vt  = off_wo + sz_w16;
  const size_t off_op  = off_vt + sz_half;
  const size_t off_sp  = off_op + sz_op;
  const size_t off_mb  = off_sp + sz_sp;
  if (ws_size < off_mb + sz_mb) return;                        // ~42 MB
  float*    lam   = (float*)(ws);
  _Float16* x16   = (_Float16*)(ws + off_x16);
  _Float16* w16v  = (_Float16*)(ws + off_wv);
  _Float16* w16o  = (_Float16*)(ws + off_wo);
  _Float16* Vt    = (_Float16*)(ws + off_vt);
  _Float16* Opart = (_Float16*)(ws + off_op);
  float*    Spart = (float*)(ws + off_sp);
  unsigned short* mbits = (unsigned short*)(ws + off_mb);

  prep2_kernel<<<dim3(5633), dim3(256), 0, stream>>>(
      x, v_w, out_w, umask, lq1, lk1, lq2, lk2, x16, w16v, w16o, mbits, lam);
  hgemmT_v<<<dim3(32, 8), dim3(256), 0, stream>>>(w16v, x16, Vt);
  fused_attn11<<<dim3(kN / 16, 8, kB), dim3(256), 0, stream>>>(
      u, mbits, uw, ubias, Vt, Opart, Spart);
  combine_out<<<dim3(2, kN / 16, kB), dim3(256), 0, stream>>>(
      Opart, Spart, lam, ln_w, ln_b, w16o, out);
}

// Round 20
// 111.629 us; speedup vs baseline: 1.2803x; 1.2803x over previous
//
#include <hip/hip_runtime.h>
#include <math.h>

typedef _Float16 f16x8 __attribute__((ext_vector_type(8)));
typedef _Float16 f16x4 __attribute__((ext_vector_type(4)));
typedef float    f32x4 __attribute__((ext_vector_type(4)));

constexpr int kB  = 4;
constexpr int kN  = 512;
constexpr int kE  = 512;
constexpr int kH  = 8;
constexpr int kH2 = 16;
constexpr int kC  = 64;
constexpr int kDV = 64;
constexpr float kLamInit = 0.2f;

// ---- prep2 (R8/R14-validated): f32->f16 cvt, lambda, umask bitpack ---------
__global__ __launch_bounds__(256) void prep2_kernel(
    const float* __restrict__ x, const float* __restrict__ vw,
    const float* __restrict__ ow, const int* __restrict__ umask,
    const float* __restrict__ lq1, const float* __restrict__ lk1,
    const float* __restrict__ lq2, const float* __restrict__ lk2,
    _Float16* __restrict__ x16, _Float16* __restrict__ w16v,
    _Float16* __restrict__ w16o, unsigned short* __restrict__ mbits,
    float* __restrict__ lam_out) {
  const int bid = blockIdx.x;
  if (bid < 1536) {
    const float* src; _Float16* dst; int base;
    if (bid < 1024)      { src = x;  dst = x16;  base = bid; }
    else if (bid < 1280) { src = vw; dst = w16v; base = bid - 1024; }
    else                 { src = ow; dst = w16o; base = bid - 1280; }
    const int i = base * 256 + threadIdx.x;
    const float4 v = ((const float4*)src)[i];
    union { _Float16 h[4]; uint2 u2; } P;
    P.h[0]=(_Float16)v.x; P.h[1]=(_Float16)v.y;
    P.h[2]=(_Float16)v.z; P.h[3]=(_Float16)v.w;
    *(uint2*)(dst + i * 4) = P.u2;
  } else if (bid == 1536) {
    if (threadIdx.x < 64) {
      float s1 = 0.f, s2 = 0.f;
      for (int i = threadIdx.x; i < kE; i += 64) { s1 += lq1[i]*lk1[i]; s2 += lq2[i]*lk2[i]; }
      #pragma unroll
      for (int o = 32; o; o >>= 1) { s1 += __shfl_xor(s1, o); s2 += __shfl_xor(s2, o); }
      if (threadIdx.x == 0) lam_out[0] = expf(s1) - expf(s2) + kLamInit;
    }
  } else {
    const int i = (bid - 1537) * 256 + threadIdx.x;  // (b*kN+k)*kN+q
    const int4* src = (const int4*)(umask + (size_t)i * kH2);
    unsigned int w = 0;
    #pragma unroll
    for (int c = 0; c < 4; ++c) {
      const int4 m = src[c];
      w |= (m.x & 1) << (c * 4 + 0);
      w |= (m.y & 1) << (c * 4 + 1);
      w |= (m.z & 1) << (c * 4 + 2);
      w |= (m.w & 1) << (c * 4 + 3);
    }
    mbits[i] = (unsigned short)w;
  }
}

// ---- hgemmT_v (R7-validated): Vt[b][h][d][n] = (x @ v_w^T)^T ---------------
__global__ __launch_bounds__(256) void hgemmT_v(const _Float16* __restrict__ W16,
                                                const _Float16* __restrict__ X16,
                                                _Float16* __restrict__ Vt) {
  const int tid = threadIdx.x, lane = tid & 63, wv = tid >> 6;
  const int l15 = lane & 15, l4 = lane >> 4;
  const int f0 = blockIdx.y * 64 + wv * 16;
  const int n0 = blockIdx.x * 64;
  f32x4 acc[4] = {{0,0,0,0},{0,0,0,0},{0,0,0,0},{0,0,0,0}};
  const _Float16* Ap = W16 + (size_t)(f0 + l15) * kE + l4 * 8;
  const _Float16* Bp = X16 + (size_t)(n0 + l15) * kE + l4 * 8;
  for (int k0 = 0; k0 < kE; k0 += 32) {
    const f16x8 af = *(const f16x8*)(Ap + k0);
    #pragma unroll
    for (int t = 0; t < 4; ++t) {
      const f16x8 bf = *(const f16x8*)(Bp + (size_t)t * 16 * kE + k0);
      acc[t] = __builtin_amdgcn_mfma_f32_16x16x32_f16(af, bf, acc[t], 0, 0, 0);
    }
  }
  #pragma unroll
  for (int t = 0; t < 4; ++t)
    #pragma unroll
    for (int r = 0; r < 4; ++r) {
      const int f  = f0 + l4 * 4 + r;
      const int ng = n0 + t * 16 + l15;
      const int bb = ng >> 9, n = ng & 511;
      Vt[(((size_t)((bb * kH + (f >> 6)) * kDV) + (f & 63)) * kN) + n] = (_Float16)acc[t][r];
    }
}

// ---- fused v8 (R14-validated): R7 structure + bitpacked masks + mask prefetch
// grid (qt 32, kh 4, b 4) x 512 thr; 8 waves (wave = 1 head); 16 waves/CU.
__global__ __launch_bounds__(512, 4) void fused_attn8(
    const float* __restrict__ u, const unsigned short* __restrict__ mbits,
    const float* __restrict__ uw, const float* __restrict__ ub,
    const _Float16* __restrict__ Vt,
    _Float16* __restrict__ Opart, float* __restrict__ Spart) {
  __shared__ _Float16 P[16 * 648];
  __shared__ float S_lds[8][16][17];
  const int tid = threadIdx.x, lane = tid & 63, wv = tid >> 6;  // wv 0..7
  const int l15 = lane & 15, l4 = lane >> 4;
  const int qt = blockIdx.x, kh = blockIdx.y, b = blockIdx.z;
  const int q0 = qt * 16;
  const int kstart = kh * 128;

  f16x8 bfrag[2];
  #pragma unroll
  for (int ch = 0; ch < 2; ++ch) {
    const float* wp = uw + l15 * 64 + ch * 32 + l4 * 8;
    const float4 wa = *(const float4*)wp;
    const float4 wb = *(const float4*)(wp + 4);
    f16x8 bf;
    bf[0]=(_Float16)wa.x; bf[1]=(_Float16)wa.y; bf[2]=(_Float16)wa.z; bf[3]=(_Float16)wa.w;
    bf[4]=(_Float16)wb.x; bf[5]=(_Float16)wb.y; bf[6]=(_Float16)wb.z; bf[7]=(_Float16)wb.w;
    bfrag[ch] = bf;
  }
  const float bias = ub[l15];

  // mask base: u64 covering q0+l4*4 .. +3 (bit r*16+l15 -> (q=+r, h2=l15))
  const unsigned short* mb0 = mbits + (size_t)(b * kN) * kN + q0 + l4 * 4;

  float s_acc[4] = {};
  f32x4 oacc[2][4];
  #pragma unroll
  for (int s = 0; s < 2; ++s)
    #pragma unroll
    for (int d = 0; d < 4; ++d) oacc[s][d] = (f32x4){0,0,0,0};

  // prologue: masks for tile 0
  unsigned long long pm[4];
  #pragma unroll
  for (int kk = 0; kk < 4; ++kk)
    pm[kk] = *(const unsigned long long*)(mb0 + (size_t)(kstart + wv * 4 + kk) * kN);

  for (int t = 0; t < 4; ++t) {
    const int k0 = kstart + t * 32;
    // ---- phase A: ue + exp for this wave's 4 k's ----
    _Float16 vals[4][4];
    #pragma unroll
    for (int kk = 0; kk < 4; ++kk) {
      const int k = k0 + wv * 4 + kk;
      const float* up = u + (((size_t)(b * kN + k)) * kN + q0 + l15) * kC + l4 * 8;
      f32x4 acc = {0.f, 0.f, 0.f, 0.f};
      #pragma unroll
      for (int ch = 0; ch < 2; ++ch) {
        const float4 a0 = *(const float4*)(up + ch * 32);
        const float4 a1 = *(const float4*)(up + ch * 32 + 4);
        f16x8 af;
        af[0]=(_Float16)a0.x; af[1]=(_Float16)a0.y; af[2]=(_Float16)a0.z; af[3]=(_Float16)a0.w;
        af[4]=(_Float16)a1.x; af[5]=(_Float16)a1.y; af[6]=(_Float16)a1.z; af[7]=(_Float16)a1.w;
        acc = __builtin_amdgcn_mfma_f32_16x16x32_f16(af, bfrag[ch], acc, 0, 0, 0);
      }
      #pragma unroll
      for (int r = 0; r < 4; ++r) {
        const float e = ((pm[kk] >> (r * 16 + l15)) & 1ULL) ? 0.f : __expf(acc[r] + bias);
        s_acc[r] += e;
        vals[r][kk] = (_Float16)e;
      }
    }
    #pragma unroll
    for (int r = 0; r < 4; ++r) {
      union { _Float16 h[4]; uint2 u2; } PK;
      #pragma unroll
      for (int kk = 0; kk < 4; ++kk) PK.h[kk] = vals[r][kk];
      *(uint2*)&P[l15 * 648 + (l4 * 4 + r) * 40 + wv * 4] = PK.u2;
    }
    __syncthreads();  // all P writes visible
    // ---- prefetch next tile's masks (8 VGPR, in flight through phase B) ----
    if (t < 3) {
      #pragma unroll
      for (int kk = 0; kk < 4; ++kk)
        pm[kk] = *(const unsigned long long*)(mb0 + (size_t)(k0 + 32 + wv * 4 + kk) * kN);
    }
    // ---- phase B: PV via MFMA; wave's head h = wv ----
    f16x8 va[4];
    #pragma unroll
    for (int dt = 0; dt < 4; ++dt)
      va[dt] = *(const f16x8*)(Vt + (((size_t)((b * kH + wv) * kDV + dt * 16 + l15)) * kN) + k0 + l4 * 8);
    #pragma unroll
    for (int s = 0; s < 2; ++s) {
      const f16x8 pb = *(const f16x8*)&P[(wv * 2 + s) * 648 + l15 * 40 + l4 * 8];
      #pragma unroll
      for (int dt = 0; dt < 4; ++dt)
        oacc[s][dt] = __builtin_amdgcn_mfma_f32_16x16x32_f16(va[dt], pb, oacc[s][dt], 0, 0, 0);
    }
    __syncthreads();  // all P reads done before next tile's writes
  }

  // ---- epilogue ----
  #pragma unroll
  for (int r = 0; r < 4; ++r) S_lds[wv][l15][l4 * 4 + r] = s_acc[r];
  __syncthreads();
  const int blk = (b * 4 + kh) * 32 + qt;
  if (tid < 256) {
    const int h2 = tid >> 4, q = tid & 15;
    float S = 0.f;
    #pragma unroll
    for (int j = 0; j < 8; ++j) S += S_lds[j][h2][q];
    Spart[(size_t)blk * 256 + h2 * 16 + q] = S;
  }
  _Float16* ob = Opart + (size_t)blk * 16384;
  #pragma unroll
  for (int s = 0; s < 2; ++s)
    #pragma unroll
    for (int dt = 0; dt < 4; ++dt)
      #pragma unroll
      for (int r = 0; r < 4; ++r)
        ob[((size_t)(s * 8 + wv) * 64 + dt * 16 + l4 * 4 + r) * 16 + l15] =
            (_Float16)oacc[s][dt][r];
}

// ---- combine_out (R13/R14-validated): combine + LN + out-projection GEMM ---
__global__ __launch_bounds__(256) void combine_out(
    const _Float16* __restrict__ Opart, const float* __restrict__ Spart,
    const float* __restrict__ lam_p, const float* __restrict__ ln_w,
    const float* __restrict__ ln_b, const _Float16* __restrict__ w16o,
    float* __restrict__ out) {
  __shared__ _Float16 a_lds[16][520];
  __shared__ float vsh[64][17];
  __shared__ float inv_sh[2][16];
  const int tid = threadIdx.x;
  const int fh = blockIdx.x, qt = blockIdx.y, b = blockIdx.z;
  const float lam = lam_p[0];

  for (int h = 0; h < 8; ++h) {
    if (tid < 32) {
      const int s = tid >> 4, q = tid & 15;
      float S = 0.f;
      #pragma unroll
      for (int kh = 0; kh < 4; ++kh)
        S += Spart[(size_t)((b * 4 + kh) * 32 + qt) * 256 + (h * 2 + s) * 16 + q];
      inv_sh[s][q] = (s ? lam : 1.0f) / S;
    }
    float a0[4] = {}, a1[4] = {};
    #pragma unroll
    for (int kh = 0; kh < 4; ++kh) {
      const size_t base = (size_t)((b * 4 + kh) * 32 + qt) * 16384;
      const f16x4 p0 = *(const f16x4*)(Opart + base + (size_t)(0 * 8 + h) * 1024 + tid * 4);
      const f16x4 p1 = *(const f16x4*)(Opart + base + (size_t)(1 * 8 + h) * 1024 + tid * 4);
      #pragma unroll
      for (int j = 0; j < 4; ++j) { a0[j] += (float)p0[j]; a1[j] += (float)p1[j]; }
    }
    __syncthreads();  // inv_sh ready; prev head's vsh reads complete
    {
      const int d = tid >> 2, q0i = (tid & 3) * 4;
      #pragma unroll
      for (int j = 0; j < 4; ++j)
        vsh[d][q0i + j] = a0[j] * inv_sh[0][q0i + j] - a1[j] * inv_sh[1][q0i + j];
    }
    __syncthreads();
    const int q = tid >> 4, i = tid & 15;
    float vv[4], s1 = 0.f, s2 = 0.f;
    #pragma unroll
    for (int jj = 0; jj < 4; ++jj) {
      vv[jj] = vsh[i * 4 + jj][q];
      s1 += vv[jj]; s2 += vv[jj] * vv[jj];
    }
    #pragma unroll
    for (int o = 1; o < 16; o <<= 1) { s1 += __shfl_xor(s1, o); s2 += __shfl_xor(s2, o); }
    const float mu = s1 * (1.0f / kDV);
    const float var = s2 * (1.0f / kDV) - mu * mu;
    const float rstd = rsqrtf(var + 1e-5f);
    #pragma unroll
    for (int jj = 0; jj < 4; ++jj)
      a_lds[q][h * kDV + i * 4 + jj] =
          (_Float16)((vv[jj] - mu) * rstd * ln_w[i * 4 + jj] + ln_b[i * 4 + jj]);
  }
  __syncthreads();  // a_lds complete

  const int lane = tid & 63, wv = tid >> 6;
  const int l15 = lane & 15, l4 = lane >> 4;
  const int f0 = fh * 256 + wv * 64;
  f32x4 acc[4] = {{0,0,0,0},{0,0,0,0},{0,0,0,0},{0,0,0,0}};
  const _Float16* Wp = w16o + (size_t)(f0 + l15) * kE + l4 * 8;
  for (int k0 = 0; k0 < kE; k0 += 32) {
    const f16x8 af = *(const f16x8*)&a_lds[l15][k0 + l4 * 8];
    #pragma unroll
    for (int ft = 0; ft < 4; ++ft) {
      const f16x8 bf = *(const f16x8*)(Wp + (size_t)ft * 16 * kE + k0);
      acc[ft] = __builtin_amdgcn_mfma_f32_16x16x32_f16(af, bf, acc[ft], 0, 0, 0);
    }
  }
  #pragma unroll
  for (int ft = 0; ft < 4; ++ft)
    #pragma unroll
    for (int r = 0; r < 4; ++r)
      out[(size_t)(b * kN + qt * 16 + l4 * 4 + r) * kE + f0 + ft * 16 + l15] = acc[ft][r];
}

// ----------------------------------------------------------------------------
extern "C" void kernel_launch(void* const* d_in, const int* in_sizes, int n_in,
                              void* d_out, int out_size, void* d_ws, size_t ws_size,
                              hipStream_t stream) {
  const float* x     = (const float*)d_in[0];
  const float* u     = (const float*)d_in[1];
  const int*   umask = (const int*)d_in[2];
  const float* v_w   = (const float*)d_in[3];
  const float* out_w = (const float*)d_in[4];
  const float* uw    = (const float*)d_in[5];
  const float* ubias = (const float*)d_in[6];
  const float* lq1   = (const float*)d_in[7];
  const float* lk1   = (const float*)d_in[8];
  const float* lq2   = (const float*)d_in[9];
  const float* lk2   = (const float*)d_in[10];
  const float* ln_w  = (const float*)d_in[11];
  const float* ln_b  = (const float*)d_in[12];
  float* out = (float*)d_out;

  char* ws = (char*)d_ws;
  const size_t sz_half = (size_t)kB * kN * kE * 2;             // 2 MB
  const size_t sz_w16  = (size_t)kE * kE * 2;                  // 512 KB
  const size_t sz_op   = (size_t)512 * 16384 * 2;              // 16.78 MB (f16)
  const size_t sz_sp   = (size_t)512 * 256 * 4;                // 512 KB
  const size_t sz_mb   = (size_t)kB * kN * kN * 2;             // 2 MB
  const size_t off_x16 = 256;
  const size_t off_wv  = off_x16 + sz_half;
  const size_t off_wo  = off_wv + sz_w16;
  const size_t off_vt  = off_wo + sz_w16;
  const size_t off_op  = off_vt + sz_half;
  const size_t off_sp  = off_op + sz_op;
  const size_t off_mb  = off_sp + sz_sp;
  if (ws_size < off_mb + sz_mb) return;                        // ~24.5 MB
  float*    lam   = (float*)(ws);
  _Float16* x16   = (_Float16*)(ws + off_x16);
  _Float16* w16v  = (_Float16*)(ws + off_wv);
  _Float16* w16o  = (_Float16*)(ws + off_wo);
  _Float16* Vt    = (_Float16*)(ws + off_vt);
  _Float16* Opart = (_Float16*)(ws + off_op);
  float*    Spart = (float*)(ws + off_sp);
  unsigned short* mbits = (unsigned short*)(ws + off_mb);

  prep2_kernel<<<dim3(5633), dim3(256), 0, stream>>>(
      x, v_w, out_w, umask, lq1, lk1, lq2, lk2, x16, w16v, w16o, mbits, lam);
  hgemmT_v<<<dim3(32, 8), dim3(256), 0, stream>>>(w16v, x16, Vt);
  fused_attn8<<<dim3(kN / 16, 4, kB), dim3(512), 0, stream>>>(
      u, mbits, uw, ubias, Vt, Opart, Spart);
  combine_out<<<dim3(2, kN / 16, kB), dim3(256), 0, stream>>>(
      Opart, Spart, lam, ln_w, ln_b, w16o, out);
}

// Round 21
// 109.637 us; speedup vs baseline: 1.3035x; 1.0182x over previous
//
#include <hip/hip_runtime.h>
#include <math.h>

typedef _Float16 f16x8 __attribute__((ext_vector_type(8)));
typedef _Float16 f16x4 __attribute__((ext_vector_type(4)));
typedef float    f32x4 __attribute__((ext_vector_type(4)));

constexpr int kB  = 4;
constexpr int kN  = 512;
constexpr int kE  = 512;
constexpr int kH  = 8;
constexpr int kH2 = 16;
constexpr int kC  = 64;
constexpr int kDV = 64;
constexpr float kLamInit = 0.2f;

// ---- prep2 (R8/R14-validated): f32->f16 cvt, lambda, umask bitpack ---------
__global__ __launch_bounds__(256) void prep2_kernel(
    const float* __restrict__ x, const float* __restrict__ vw,
    const float* __restrict__ ow, const int* __restrict__ umask,
    const float* __restrict__ lq1, const float* __restrict__ lk1,
    const float* __restrict__ lq2, const float* __restrict__ lk2,
    _Float16* __restrict__ x16, _Float16* __restrict__ w16v,
    _Float16* __restrict__ w16o, unsigned short* __restrict__ mbits,
    float* __restrict__ lam_out) {
  const int bid = blockIdx.x;
  if (bid < 1536) {
    const float* src; _Float16* dst; int base;
    if (bid < 1024)      { src = x;  dst = x16;  base = bid; }
    else if (bid < 1280) { src = vw; dst = w16v; base = bid - 1024; }
    else                 { src = ow; dst = w16o; base = bid - 1280; }
    const int i = base * 256 + threadIdx.x;
    const float4 v = ((const float4*)src)[i];
    union { _Float16 h[4]; uint2 u2; } P;
    P.h[0]=(_Float16)v.x; P.h[1]=(_Float16)v.y;
    P.h[2]=(_Float16)v.z; P.h[3]=(_Float16)v.w;
    *(uint2*)(dst + i * 4) = P.u2;
  } else if (bid == 1536) {
    if (threadIdx.x < 64) {
      float s1 = 0.f, s2 = 0.f;
      for (int i = threadIdx.x; i < kE; i += 64) { s1 += lq1[i]*lk1[i]; s2 += lq2[i]*lk2[i]; }
      #pragma unroll
      for (int o = 32; o; o >>= 1) { s1 += __shfl_xor(s1, o); s2 += __shfl_xor(s2, o); }
      if (threadIdx.x == 0) lam_out[0] = expf(s1) - expf(s2) + kLamInit;
    }
  } else {
    const int i = (bid - 1537) * 256 + threadIdx.x;  // (b*kN+k)*kN+q
    const int4* src = (const int4*)(umask + (size_t)i * kH2);
    unsigned int w = 0;
    #pragma unroll
    for (int c = 0; c < 4; ++c) {
      const int4 m = src[c];
      w |= (m.x & 1) << (c * 4 + 0);
      w |= (m.y & 1) << (c * 4 + 1);
      w |= (m.z & 1) << (c * 4 + 2);
      w |= (m.w & 1) << (c * 4 + 3);
    }
    mbits[i] = (unsigned short)w;
  }
}

// ---- hgemmT_v (R7-validated): Vt[b][h][d][n] = (x @ v_w^T)^T ---------------
__global__ __launch_bounds__(256) void hgemmT_v(const _Float16* __restrict__ W16,
                                                const _Float16* __restrict__ X16,
                                                _Float16* __restrict__ Vt) {
  const int tid = threadIdx.x, lane = tid & 63, wv = tid >> 6;
  const int l15 = lane & 15, l4 = lane >> 4;
  const int f0 = blockIdx.y * 64 + wv * 16;
  const int n0 = blockIdx.x * 64;
  f32x4 acc[4] = {{0,0,0,0},{0,0,0,0},{0,0,0,0},{0,0,0,0}};
  const _Float16* Ap = W16 + (size_t)(f0 + l15) * kE + l4 * 8;
  const _Float16* Bp = X16 + (size_t)(n0 + l15) * kE + l4 * 8;
  for (int k0 = 0; k0 < kE; k0 += 32) {
    const f16x8 af = *(const f16x8*)(Ap + k0);
    #pragma unroll
    for (int t = 0; t < 4; ++t) {
      const f16x8 bf = *(const f16x8*)(Bp + (size_t)t * 16 * kE + k0);
      acc[t] = __builtin_amdgcn_mfma_f32_16x16x32_f16(af, bf, acc[t], 0, 0, 0);
    }
  }
  #pragma unroll
  for (int t = 0; t < 4; ++t)
    #pragma unroll
    for (int r = 0; r < 4; ++r) {
      const int f  = f0 + l4 * 4 + r;
      const int ng = n0 + t * 16 + l15;
      const int bb = ng >> 9, n = ng & 511;
      Vt[(((size_t)((bb * kH + (f >> 6)) * kDV) + (f & 63)) * kN) + n] = (_Float16)acc[t][r];
    }
}

// ---- fused v12: 64-k tiles (R8-validated shape) + mask prefetch (R14) ------
// grid (qt 32, kh 4, b 4) x 512 thr; 8 waves (wave = 1 head); 16 waves/CU.
// Per 64-k tile: phase A = wave's 8 k's -> P (stride 1160/72, R8-validated);
// barrier; prefetch next tile's 8 masks; phase B = 16 MFMA (2 hf x 2 s x 4 dt);
// barrier. 4 barriers per block (vs R14/R18's 8).
__global__ __launch_bounds__(512, 4) void fused_attn12(
    const float* __restrict__ u, const unsigned short* __restrict__ mbits,
    const float* __restrict__ uw, const float* __restrict__ ub,
    const _Float16* __restrict__ Vt,
    _Float16* __restrict__ Opart, float* __restrict__ Spart) {
  __shared__ _Float16 P[16 * 1160];   // 37 KB
  __shared__ float S_lds[8][16][17];
  const int tid = threadIdx.x, lane = tid & 63, wv = tid >> 6;  // wv 0..7
  const int l15 = lane & 15, l4 = lane >> 4;
  const int qt = blockIdx.x, kh = blockIdx.y, b = blockIdx.z;
  const int q0 = qt * 16;
  const int kstart = kh * 128;

  f16x8 bfrag[2];
  #pragma unroll
  for (int ch = 0; ch < 2; ++ch) {
    const float* wp = uw + l15 * 64 + ch * 32 + l4 * 8;
    const float4 wa = *(const float4*)wp;
    const float4 wb = *(const float4*)(wp + 4);
    f16x8 bf;
    bf[0]=(_Float16)wa.x; bf[1]=(_Float16)wa.y; bf[2]=(_Float16)wa.z; bf[3]=(_Float16)wa.w;
    bf[4]=(_Float16)wb.x; bf[5]=(_Float16)wb.y; bf[6]=(_Float16)wb.z; bf[7]=(_Float16)wb.w;
    bfrag[ch] = bf;
  }
  const float bias = ub[l15];

  // mask base: u64 covering q0+l4*4 .. +3 (bit r*16+l15 -> (q=+r, h2=l15))
  const unsigned short* mb0 = mbits + (size_t)(b * kN) * kN + q0 + l4 * 4;

  float s_acc[4] = {};
  f32x4 oacc[2][4];
  #pragma unroll
  for (int s = 0; s < 2; ++s)
    #pragma unroll
    for (int d = 0; d < 4; ++d) oacc[s][d] = (f32x4){0,0,0,0};

  // prologue: masks for tile 0 (this wave's 8 k's)
  unsigned long long pm[8];
  #pragma unroll
  for (int kk = 0; kk < 8; ++kk)
    pm[kk] = *(const unsigned long long*)(mb0 + (size_t)(kstart + wv * 8 + kk) * kN);

  for (int t = 0; t < 2; ++t) {
    const int k0 = kstart + t * 64;
    const int kbase = k0 + wv * 8;
    // ---- phase A: ue + exp for this wave's 8 k's ----
    _Float16 vals[4][8];
    #pragma unroll
    for (int kk = 0; kk < 8; ++kk) {
      const int k = kbase + kk;
      const float* up = u + (((size_t)(b * kN + k)) * kN + q0 + l15) * kC + l4 * 8;
      f32x4 acc = {0.f, 0.f, 0.f, 0.f};
      #pragma unroll
      for (int ch = 0; ch < 2; ++ch) {
        const float4 a0 = *(const float4*)(up + ch * 32);
        const float4 a1 = *(const float4*)(up + ch * 32 + 4);
        f16x8 af;
        af[0]=(_Float16)a0.x; af[1]=(_Float16)a0.y; af[2]=(_Float16)a0.z; af[3]=(_Float16)a0.w;
        af[4]=(_Float16)a1.x; af[5]=(_Float16)a1.y; af[6]=(_Float16)a1.z; af[7]=(_Float16)a1.w;
        acc = __builtin_amdgcn_mfma_f32_16x16x32_f16(af, bfrag[ch], acc, 0, 0, 0);
      }
      #pragma unroll
      for (int r = 0; r < 4; ++r) {
        const float e = ((pm[kk] >> (r * 16 + l15)) & 1ULL) ? 0.f : __expf(acc[r] + bias);
        s_acc[r] += e;
        vals[r][kk] = (_Float16)e;
      }
    }
    #pragma unroll
    for (int r = 0; r < 4; ++r) {
      union { _Float16 h[8]; int4 v; } PK;
      #pragma unroll
      for (int kk = 0; kk < 8; ++kk) PK.h[kk] = vals[r][kk];
      *(int4*)&P[l15 * 1160 + (l4 * 4 + r) * 72 + wv * 8] = PK.v;
    }
    __syncthreads();  // all P writes visible
    // ---- prefetch next tile's masks (16 VGPR, in flight through phase B) ---
    if (t == 0) {
      #pragma unroll
      for (int kk = 0; kk < 8; ++kk)
        pm[kk] = *(const unsigned long long*)(mb0 + (size_t)(k0 + 64 + wv * 8 + kk) * kN);
    }
    // ---- phase B: PV via MFMA; wave's head h = wv (2 k-halves) ----
    #pragma unroll
    for (int hf = 0; hf < 2; ++hf) {
      #pragma unroll
      for (int dt = 0; dt < 4; ++dt) {
        const f16x8 va = *(const f16x8*)(Vt +
            (((size_t)((b * kH + wv) * kDV + dt * 16 + l15)) * kN) + k0 + hf * 32 + l4 * 8);
        #pragma unroll
        for (int s = 0; s < 2; ++s) {
          const f16x8 pb = *(const f16x8*)&P[(wv * 2 + s) * 1160 + l15 * 72 + hf * 32 + l4 * 8];
          oacc[s][dt] = __builtin_amdgcn_mfma_f32_16x16x32_f16(va, pb, oacc[s][dt], 0, 0, 0);
        }
      }
    }
    __syncthreads();  // all P reads done before next tile's writes
  }

  // ---- epilogue ----
  #pragma unroll
  for (int r = 0; r < 4; ++r) S_lds[wv][l15][l4 * 4 + r] = s_acc[r];
  __syncthreads();
  const int blk = (b * 4 + kh) * 32 + qt;
  if (tid < 256) {
    const int h2 = tid >> 4, q = tid & 15;
    float S = 0.f;
    #pragma unroll
    for (int j = 0; j < 8; ++j) S += S_lds[j][h2][q];
    Spart[(size_t)blk * 256 + h2 * 16 + q] = S;
  }
  _Float16* ob = Opart + (size_t)blk * 16384;
  #pragma unroll
  for (int s = 0; s < 2; ++s)
    #pragma unroll
    for (int dt = 0; dt < 4; ++dt)
      #pragma unroll
      for (int r = 0; r < 4; ++r)
        ob[((size_t)(s * 8 + wv) * 64 + dt * 16 + l4 * 4 + r) * 16 + l15] =
            (_Float16)oacc[s][dt][r];
}

// ---- combine_out (R13/R14-validated): combine + LN + out-projection GEMM ---
__global__ __launch_bounds__(256) void combine_out(
    const _Float16* __restrict__ Opart, const float* __restrict__ Spart,
    const float* __restrict__ lam_p, const float* __restrict__ ln_w,
    const float* __restrict__ ln_b, const _Float16* __restrict__ w16o,
    float* __restrict__ out) {
  __shared__ _Float16 a_lds[16][520];
  __shared__ float vsh[64][17];
  __shared__ float inv_sh[2][16];
  const int tid = threadIdx.x;
  const int fh = blockIdx.x, qt = blockIdx.y, b = blockIdx.z;
  const float lam = lam_p[0];

  for (int h = 0; h < 8; ++h) {
    if (tid < 32) {
      const int s = tid >> 4, q = tid & 15;
      float S = 0.f;
      #pragma unroll
      for (int kh = 0; kh < 4; ++kh)
        S += Spart[(size_t)((b * 4 + kh) * 32 + qt) * 256 + (h * 2 + s) * 16 + q];
      inv_sh[s][q] = (s ? lam : 1.0f) / S;
    }
    float a0[4] = {}, a1[4] = {};
    #pragma unroll
    for (int kh = 0; kh < 4; ++kh) {
      const size_t base = (size_t)((b * 4 + kh) * 32 + qt) * 16384;
      const f16x4 p0 = *(const f16x4*)(Opart + base + (size_t)(0 * 8 + h) * 1024 + tid * 4);
      const f16x4 p1 = *(const f16x4*)(Opart + base + (size_t)(1 * 8 + h) * 1024 + tid * 4);
      #pragma unroll
      for (int j = 0; j < 4; ++j) { a0[j] += (float)p0[j]; a1[j] += (float)p1[j]; }
    }
    __syncthreads();  // inv_sh ready; prev head's vsh reads complete
    {
      const int d = tid >> 2, q0i = (tid & 3) * 4;
      #pragma unroll
      for (int j = 0; j < 4; ++j)
        vsh[d][q0i + j] = a0[j] * inv_sh[0][q0i + j] - a1[j] * inv_sh[1][q0i + j];
    }
    __syncthreads();
    const int q = tid >> 4, i = tid & 15;
    float vv[4], s1 = 0.f, s2 = 0.f;
    #pragma unroll
    for (int jj = 0; jj < 4; ++jj) {
      vv[jj] = vsh[i * 4 + jj][q];
      s1 += vv[jj]; s2 += vv[jj] * vv[jj];
    }
    #pragma unroll
    for (int o = 1; o < 16; o <<= 1) { s1 += __shfl_xor(s1, o); s2 += __shfl_xor(s2, o); }
    const float mu = s1 * (1.0f / kDV);
    const float var = s2 * (1.0f / kDV) - mu * mu;
    const float rstd = rsqrtf(var + 1e-5f);
    #pragma unroll
    for (int jj = 0; jj < 4; ++jj)
      a_lds[q][h * kDV + i * 4 + jj] =
          (_Float16)((vv[jj] - mu) * rstd * ln_w[i * 4 + jj] + ln_b[i * 4 + jj]);
  }
  __syncthreads();  // a_lds complete

  const int lane = tid & 63, wv = tid >> 6;
  const int l15 = lane & 15, l4 = lane >> 4;
  const int f0 = fh * 256 + wv * 64;
  f32x4 acc[4] = {{0,0,0,0},{0,0,0,0},{0,0,0,0},{0,0,0,0}};
  const _Float16* Wp = w16o + (size_t)(f0 + l15) * kE + l4 * 8;
  for (int k0 = 0; k0 < kE; k0 += 32) {
    const f16x8 af = *(const f16x8*)&a_lds[l15][k0 + l4 * 8];
    #pragma unroll
    for (int ft = 0; ft < 4; ++ft) {
      const f16x8 bf = *(const f16x8*)(Wp + (size_t)ft * 16 * kE + k0);
      acc[ft] = __builtin_amdgcn_mfma_f32_16x16x32_f16(af, bf, acc[ft], 0, 0, 0);
    }
  }
  #pragma unroll
  for (int ft = 0; ft < 4; ++ft)
    #pragma unroll
    for (int r = 0; r < 4; ++r)
      out[(size_t)(b * kN + qt * 16 + l4 * 4 + r) * kE + f0 + ft * 16 + l15] = acc[ft][r];
}

// ----------------------------------------------------------------------------
extern "C" void kernel_launch(void* const* d_in, const int* in_sizes, int n_in,
                              void* d_out, int out_size, void* d_ws, size_t ws_size,
                              hipStream_t stream) {
  const float* x     = (const float*)d_in[0];
  const float* u     = (const float*)d_in[1];
  const int*   umask = (const int*)d_in[2];
  const float* v_w   = (const float*)d_in[3];
  const float* out_w = (const float*)d_in[4];
  const float* uw    = (const float*)d_in[5];
  const float* ubias = (const float*)d_in[6];
  const float* lq1   = (const float*)d_in[7];
  const float* lk1   = (const float*)d_in[8];
  const float* lq2   = (const float*)d_in[9];
  const float* lk2   = (const float*)d_in[10];
  const float* ln_w  = (const float*)d_in[11];
  const float* ln_b  = (const float*)d_in[12];
  float* out = (float*)d_out;

  char* ws = (char*)d_ws;
  const size_t sz_half = (size_t)kB * kN * kE * 2;             // 2 MB
  const size_t sz_w16  = (size_t)kE * kE * 2;                  // 512 KB
  const size_t sz_op   = (size_t)512 * 16384 * 2;              // 16.78 MB (f16)
  const size_t sz_sp   = (size_t)512 * 256 * 4;                // 512 KB
  const size_t sz_mb   = (size_t)kB * kN * kN * 2;             // 2 MB
  const size_t off_x16 = 256;
  const size_t off_wv  = off_x16 + sz_half;
  const size_t off_wo  = off_wv + sz_w16;
  const size_t off_vt  = off_wo + sz_w16;
  const size_t off_op  = off_vt + sz_half;
  const size_t off_sp  = off_op + sz_op;
  const size_t off_mb  = off_sp + sz_sp;
  if (ws_size < off_mb + sz_mb) return;                        // ~24.5 MB
  float*    lam   = (float*)(ws);
  _Float16* x16   = (_Float16*)(ws + off_x16);
  _Float16* w16v  = (_Float16*)(ws + off_wv);
  _Float16* w16o  = (_Float16*)(ws + off_wo);
  _Float16* Vt    = (_Float16*)(ws + off_vt);
  _Float16* Opart = (_Float16*)(ws + off_op);
  float*    Spart = (float*)(ws + off_sp);
  unsigned short* mbits = (unsigned short*)(ws + off_mb);

  prep2_kernel<<<dim3(5633), dim3(256), 0, stream>>>(
      x, v_w, out_w, umask, lq1, lk1, lq2, lk2, x16, w16v, w16o, mbits, lam);
  hgemmT_v<<<dim3(32, 8), dim3(256), 0, stream>>>(w16v, x16, Vt);
  fused_attn12<<<dim3(kN / 16, 4, kB), dim3(512), 0, stream>>>(
      u, mbits, uw, ubias, Vt, Opart, Spart);
  combine_out<<<dim3(2, kN / 16, kB), dim3(256), 0, stream>>>(
      Opart, Spart, lam, ln_w, ln_b, w16o, out);
}